// Round 1
// baseline (1120.100 us; speedup 1.0000x reference)
//
#include <hip/hip_runtime.h>
#include <math.h>

#define N 8192
#define NF4 2048  // N/4 float4s per row

__device__ __forceinline__ float wave_max(float m) {
#pragma unroll
  for (int off = 32; off > 0; off >>= 1) m = fmaxf(m, __shfl_xor(m, off, 64));
  return m;
}
__device__ __forceinline__ float wave_sum(float s) {
#pragma unroll
  for (int off = 32; off > 0; off >>= 1) s += __shfl_xor(s, off, 64);
  return s;
}

// u[row] = logsumexp_j(s[row][j] - v[j]); if !use_v, v treated as 0.
__global__ __launch_bounds__(256) void row_lse(const float* __restrict__ s,
                                               const float* __restrict__ v,
                                               float* __restrict__ u,
                                               int use_v) {
  const int row = blockIdx.x;
  const float4* s4 = (const float4*)s + (size_t)row * NF4;
  const float4* v4 = (const float4*)v;
  const int t = threadIdx.x;
  float x[32];
  float m = -INFINITY;
#pragma unroll
  for (int k = 0; k < 8; ++k) {
    const int idx = t + k * 256;
    float4 sv = s4[idx];
    float4 vv;
    if (use_v) vv = v4[idx];
    else vv = make_float4(0.f, 0.f, 0.f, 0.f);
    const float a0 = sv.x - vv.x, a1 = sv.y - vv.y;
    const float a2 = sv.z - vv.z, a3 = sv.w - vv.w;
    x[4 * k + 0] = a0; x[4 * k + 1] = a1; x[4 * k + 2] = a2; x[4 * k + 3] = a3;
    m = fmaxf(m, fmaxf(fmaxf(a0, a1), fmaxf(a2, a3)));
  }
  __shared__ float red[8];
  const int wid = t >> 6, lane = t & 63;
  m = wave_max(m);
  if (lane == 0) red[wid] = m;
  __syncthreads();
  const float bm = fmaxf(fmaxf(red[0], red[1]), fmaxf(red[2], red[3]));
  float acc = 0.f;
#pragma unroll
  for (int i = 0; i < 32; ++i) acc += __expf(x[i] - bm);
  acc = wave_sum(acc);
  if (lane == 0) red[4 + wid] = acc;
  __syncthreads();
  if (t == 0) u[row] = bm + __logf(red[4] + red[5] + red[6] + red[7]);
}

// Partial column LSE over a row-chunk: per column, online (m, t) pair.
__global__ __launch_bounds__(256) void col_partial(const float* __restrict__ s,
                                                   const float* __restrict__ u,
                                                   float* __restrict__ pm,
                                                   float* __restrict__ pt,
                                                   int rows_per_chunk) {
  const int col4 = blockIdx.x * 256 + threadIdx.x;  // float4 column index, 0..2047
  const int row0 = blockIdx.y * rows_per_chunk;
  const float4* s4 = (const float4*)s;
  float m0 = -INFINITY, m1 = -INFINITY, m2 = -INFINITY, m3 = -INFINITY;
  float t0 = 0.f, t1 = 0.f, t2 = 0.f, t3 = 0.f;
  for (int r = 0; r < rows_per_chunk; ++r) {
    const int row = row0 + r;
    const float ur = u[row];
    const float4 sv = s4[(size_t)row * NF4 + col4];
    {
      const float a = sv.x - ur;
      const float nm = fmaxf(m0, a);
      t0 = t0 * __expf(m0 - nm) + __expf(a - nm);
      m0 = nm;
    }
    {
      const float a = sv.y - ur;
      const float nm = fmaxf(m1, a);
      t1 = t1 * __expf(m1 - nm) + __expf(a - nm);
      m1 = nm;
    }
    {
      const float a = sv.z - ur;
      const float nm = fmaxf(m2, a);
      t2 = t2 * __expf(m2 - nm) + __expf(a - nm);
      m2 = nm;
    }
    {
      const float a = sv.w - ur;
      const float nm = fmaxf(m3, a);
      t3 = t3 * __expf(m3 - nm) + __expf(a - nm);
      m3 = nm;
    }
  }
  const size_t o = (size_t)blockIdx.y * NF4 + col4;
  ((float4*)pm)[o] = make_float4(m0, m1, m2, m3);
  ((float4*)pt)[o] = make_float4(t0, t1, t2, t3);
}

// v[j] = combine of per-chunk (m, t) pairs: M + log(sum t_c * exp(m_c - M))
__global__ __launch_bounds__(256) void col_combine(const float* __restrict__ pm,
                                                   const float* __restrict__ pt,
                                                   float* __restrict__ v,
                                                   int nchunk) {
  const int j = blockIdx.x * 256 + threadIdx.x;  // 0..8191
  float M = -INFINITY;
  for (int c = 0; c < nchunk; ++c) M = fmaxf(M, pm[(size_t)c * N + j]);
  float T = 0.f;
  for (int c = 0; c < nchunk; ++c)
    T += pt[(size_t)c * N + j] * __expf(pm[(size_t)c * N + j] - M);
  v[j] = M + __logf(T);
}

// out = exp(s - u_i - v_j)
__global__ __launch_bounds__(256) void finalize_k(const float* __restrict__ s,
                                                  const float* __restrict__ u,
                                                  const float* __restrict__ v,
                                                  float* __restrict__ out) {
  const size_t idx = (size_t)blockIdx.x * 256 + threadIdx.x;  // float4 index
  const int row = (int)(idx >> 11);
  const int c4 = (int)(idx & 2047);
  const float4 sv = ((const float4*)s)[idx];
  const float4 vv = ((const float4*)v)[c4];
  const float ur = u[row];
  float4 o;
  o.x = __expf(sv.x - ur - vv.x);
  o.y = __expf(sv.y - ur - vv.y);
  o.z = __expf(sv.z - ur - vv.z);
  o.w = __expf(sv.w - ur - vv.w);
  ((float4*)out)[idx] = o;
}

extern "C" void kernel_launch(void* const* d_in, const int* in_sizes, int n_in,
                              void* d_out, int out_size, void* d_ws, size_t ws_size,
                              hipStream_t stream) {
  const float* s = (const float*)d_in[0];
  float* out = (float*)d_out;
  float* ws = (float*)d_ws;
  float* u = ws;           // 8192 floats
  float* v = ws + N;       // 8192 floats
  float* pm = ws + 2 * N;  // nchunk * 8192 floats

  // pick chunk count that fits the workspace: 2N + 2*nchunk*N floats needed
  size_t avail_floats = ws_size / sizeof(float);
  int nchunk = 128;
  while (nchunk > 1 &&
         (size_t)(2 * N) + (size_t)2 * nchunk * N > avail_floats)
    nchunk >>= 1;
  const int rows_per_chunk = N / nchunk;
  float* pt = pm + (size_t)nchunk * N;

  // it 0 (rows, v == 0)
  row_lse<<<N, 256, 0, stream>>>(s, v, u, 0);
  for (int it = 1; it < 10; ++it) {
    if (it & 1) {
      col_partial<<<dim3(8, nchunk), 256, 0, stream>>>(s, u, pm, pt,
                                                       rows_per_chunk);
      col_combine<<<N / 256, 256, 0, stream>>>(pm, pt, v, nchunk);
    } else {
      row_lse<<<N, 256, 0, stream>>>(s, v, u, 1);
    }
  }
  finalize_k<<<(N * NF4) / 256, 256, 0, stream>>>(s, u, v, out);
}